// Round 1
// baseline (107.533 us; speedup 1.0000x reference)
//
#include <hip/hip_runtime.h>

// MorphoMLP: y = relu(maxplus(relu(maxplus(x,W1)), W2)), fp32.
// B=512, IN=512, HID=1024, OUT=512.
// R3: morpho inner loop goes LDS-free (direct global/L1 operand reads) and
//     packs adds as v_pk_add_f32 via float2 ext-vectors.
//   transpose3 -> morpho3 L1 (128x64 tile, splitK=8, 512 blk) -> combineH
//   -> morpho3 L2 (splitK=16, 512 blk) -> combineY (max16 + relu + transpose)
// ws: xT 1MB | W1T 2MB | W2T 2MB | hp 16MB | A2 2MB | yp 16MB  = 39MB

#define WS_XT   0                          // [512][512]    x^T  [k][b]
#define WS_W1T  (512 * 512)                // [512][1024]   W1^T [k][j]
#define WS_W2T  (WS_W1T + 512 * 1024)      // [1024][512]   W2^T [k2][o]
#define WS_HP   (WS_W2T + 1024 * 512)      // [8][1024][512]  L1 partials
#define WS_A2   (WS_HP + 8 * 1024 * 512)   // [1024][512]   relu(h)^T [k2][b]
#define WS_YP   (WS_A2 + 1024 * 512)       // [16][512][512]  L2 partials

typedef float f32x2 __attribute__((ext_vector_type(2)));

// ---------------------------------------------------------------------------
// Fused transpose of x (512x512), W1 (1024x512), W2 (512x1024) into ws.
__global__ __launch_bounds__(256) void transpose3(const float* __restrict__ x,
                                                  const float* __restrict__ W1,
                                                  const float* __restrict__ W2,
                                                  float* __restrict__ ws) {
    __shared__ float t[32][33];
    const int id = blockIdx.x;
    const float* src;
    float* dst;
    int R, C, rt, ct;
    if (id < 256) {
        src = x;  dst = ws + WS_XT;  R = 512;  C = 512;
        rt = id >> 4;          ct = id & 15;
    } else if (id < 768) {
        int b = id - 256;
        src = W1; dst = ws + WS_W1T; R = 1024; C = 512;
        rt = b >> 4;           ct = b & 15;
    } else {
        int b = id - 768;
        src = W2; dst = ws + WS_W2T; R = 512;  C = 1024;
        rt = b >> 5;           ct = b & 31;
    }
    const int tx = threadIdx.x & 31, ty = threadIdx.x >> 5;
    const int r0 = rt * 32, c0 = ct * 32;
#pragma unroll
    for (int r = 0; r < 4; r++)
        t[ty + 8 * r][tx] = src[(size_t)(r0 + ty + 8 * r) * C + c0 + tx];
    __syncthreads();
#pragma unroll
    for (int r = 0; r < 4; r++)
        dst[(size_t)(c0 + ty + 8 * r) * R + r0 + tx] = t[tx][ty + 8 * r];
}

// ---------------------------------------------------------------------------
// Max-plus tile kernel, LDS-free.
// A: [K][512] K-major activations; W: [K][JDIM] K-major weights.
// Block tile: 128 j x 64 b x 64 k. 256 threads, 8j x 4b fragment/thread.
// Operands come straight from global (active window ~1.5KB/2k -> L1/L2 hit).
// Adds packed as v_pk_add_f32 (f32x2), max pairs fuse to v_max3_f32.
// Stores raw partial (no relu) transposed: P[z][j][b].
template <int JDIM>
__global__ __launch_bounds__(256, 2) void morpho3(const float* __restrict__ A,
                                                  const float* __restrict__ W,
                                                  float* __restrict__ P) {
    const int t  = threadIdx.x;
    const int tx = t & 15;           // b frag: b0 + tx*4 + {0..3}
    const int ty = t >> 4;           // j frag: j0 + ty*8 + {0..7}
    const int j0 = blockIdx.x * 128;
    const int b0 = blockIdx.y * 64;
    const int k0 = blockIdx.z * 64;

    // per-k row strides (in float4): A row = 512 floats = 128 f4; W row = JDIM/4 f4
    const float4* Ap = (const float4*)(A + (size_t)k0 * 512) + (b0 >> 2) + tx;
    const float4* Wp = (const float4*)(W + (size_t)k0 * JDIM) + (j0 >> 2) + ty * 2;

    float acc[8][4];
#pragma unroll
    for (int jj = 0; jj < 8; jj++)
#pragma unroll
        for (int i = 0; i < 4; i++) acc[jj][i] = -3.402823466e38f;

    // ---- inner max-plus: 2 k's per iter; packed adds + v_max3 merge ----
#pragma unroll 4
    for (int kk = 0; kk < 64; kk += 2) {
        const float4 a0  = Ap[0];
        const float4 a1  = Ap[128];
        const float4 w0a = Wp[0];
        const float4 w0b = Wp[1];
        const float4 w1a = Wp[JDIM / 4];
        const float4 w1b = Wp[JDIM / 4 + 1];
        const f32x2 a0lo = {a0.x, a0.y}, a0hi = {a0.z, a0.w};
        const f32x2 a1lo = {a1.x, a1.y}, a1hi = {a1.z, a1.w};
#define UPDP(JJ, W0C, W1C)                                                  \
    {                                                                       \
        const f32x2 wa  = {(W0C), (W0C)};                                   \
        const f32x2 wb  = {(W1C), (W1C)};                                   \
        const f32x2 s0l = a0lo + wa, s0h = a0hi + wa;                       \
        const f32x2 s1l = a1lo + wb, s1h = a1hi + wb;                       \
        acc[JJ][0] = fmaxf(fmaxf(acc[JJ][0], s0l.x), s1l.x);                \
        acc[JJ][1] = fmaxf(fmaxf(acc[JJ][1], s0l.y), s1l.y);                \
        acc[JJ][2] = fmaxf(fmaxf(acc[JJ][2], s0h.x), s1h.x);                \
        acc[JJ][3] = fmaxf(fmaxf(acc[JJ][3], s0h.y), s1h.y);                \
    }
        UPDP(0, w0a.x, w1a.x)
        UPDP(1, w0a.y, w1a.y)
        UPDP(2, w0a.z, w1a.z)
        UPDP(3, w0a.w, w1a.w)
        UPDP(4, w0b.x, w1b.x)
        UPDP(5, w0b.y, w1b.y)
        UPDP(6, w0b.z, w1b.z)
        UPDP(7, w0b.w, w1b.w)
#undef UPDP
        Ap += 256;                 // 2 k rows of A (2*128 f4)
        Wp += JDIM / 2;            // 2 k rows of W (2*JDIM/4 f4)
    }

    // ---- store transposed partial: P[z][j][b], float4 over b (coalesced) ----
    float* Pp = P + (size_t)blockIdx.z * JDIM * 512;
#pragma unroll
    for (int jj = 0; jj < 8; jj++) {
        const float4 v = make_float4(acc[jj][0], acc[jj][1], acc[jj][2], acc[jj][3]);
        *(float4*)(Pp + (size_t)(j0 + ty * 8 + jj) * 512 + b0 + tx * 4) = v;
    }
}

// ---------------------------------------------------------------------------
// combineH: A2[j][b] = relu(max_z hp[z][j][b]).  Already K-major for L2.
// 512 blocks x 256 thr x 1 float4 = 512K floats.
__global__ __launch_bounds__(256) void combineH(const float* __restrict__ hp,
                                                float* __restrict__ A2) {
    const int i = blockIdx.x * 256 + threadIdx.x;   // float4 index
    const float4* p = (const float4*)hp;
    float4 m = p[i];
#pragma unroll
    for (int z = 1; z < 8; z++) {
        const float4 v = p[i + z * 131072];         // 512K floats / 4
        m.x = fmaxf(m.x, v.x);
        m.y = fmaxf(m.y, v.y);
        m.z = fmaxf(m.z, v.z);
        m.w = fmaxf(m.w, v.w);
    }
    m.x = fmaxf(m.x, 0.0f);
    m.y = fmaxf(m.y, 0.0f);
    m.z = fmaxf(m.z, 0.0f);
    m.w = fmaxf(m.w, 0.0f);
    ((float4*)A2)[i] = m;
}

// ---------------------------------------------------------------------------
// combineY: out[b][o] = relu(max_z yp[z][o][b]); 16 partials + transpose.
__global__ __launch_bounds__(256) void combineY(const float* __restrict__ yp,
                                                float* __restrict__ out) {
    __shared__ float t[32][33];
    const int id = blockIdx.x;
    const int ot = id & 15, bt = id >> 4;
    const int tx = threadIdx.x & 31, ty = threadIdx.x >> 5;
    const int o0 = ot * 32, b0 = bt * 32;
#pragma unroll
    for (int r = 0; r < 4; r++) {
        const int o   = o0 + ty + 8 * r;
        const int idx = o * 512 + b0 + tx;
        float m = yp[idx];
#pragma unroll
        for (int z = 1; z < 16; z++) m = fmaxf(m, yp[idx + z * 262144]);
        t[ty + 8 * r][tx] = fmaxf(m, 0.0f);
    }
    __syncthreads();
#pragma unroll
    for (int r = 0; r < 4; r++)
        out[(b0 + ty + 8 * r) * 512 + o0 + tx] = t[tx][ty + 8 * r];
}

// ---------------------------------------------------------------------------
extern "C" void kernel_launch(void* const* d_in, const int* in_sizes, int n_in,
                              void* d_out, int out_size, void* d_ws, size_t ws_size,
                              hipStream_t stream) {
    (void)in_sizes; (void)n_in; (void)out_size; (void)ws_size;
    const float* x  = (const float*)d_in[0];
    const float* W1 = (const float*)d_in[1];
    const float* W2 = (const float*)d_in[2];
    float* ws  = (float*)d_ws;
    float* out = (float*)d_out;

    // 1) K-major transposes of x, W1, W2
    transpose3<<<1280, 256, 0, stream>>>(x, W1, W2, ws);

    // 2) L1: hp[8][1024][512]; grid 8(j) x 8(b) x 8(kz), Kchunk=64
    morpho3<1024><<<dim3(8, 8, 8), 256, 0, stream>>>(
        ws + WS_XT, ws + WS_W1T, ws + WS_HP);

    // 3) combine 8 partials + relu -> A2[k2][b]
    combineH<<<512, 256, 0, stream>>>(ws + WS_HP, ws + WS_A2);

    // 4) L2: yp[16][512][512]; grid 4(j) x 8(b) x 16(kz), Kchunk=64
    morpho3<512><<<dim3(4, 8, 16), 256, 0, stream>>>(
        ws + WS_A2, ws + WS_W2T, ws + WS_YP);

    // 5) combine 16 partials + relu + transpose -> d_out[b][o]
    combineY<<<256, 256, 0, stream>>>(ws + WS_YP, out);
}